// Round 2
// 1757.928 us; speedup vs baseline: 1.0848x; 1.0848x over previous
//
#include <hip/hip_runtime.h>
#include <hip/hip_bf16.h>
#include <stdint.h>

typedef __attribute__((ext_vector_type(8))) short bf16x8;
typedef __attribute__((ext_vector_type(4))) float f32x4;
typedef __hip_bfloat16 bf16;

typedef const __attribute__((address_space(1))) void* gas_ptr;
typedef __attribute__((address_space(3))) void* las_ptr;

__device__ __forceinline__ void async_load16(const bf16* g, bf16* l) {
  __builtin_amdgcn_global_load_lds((gas_ptr)g, (las_ptr)l, 16, 0, 0);
}

// Raw barrier (no vmcnt drain!) + compile-time memory fences so loads/stages
// cannot be moved across it by the optimizer.
#define BAR()                                   \
  do {                                          \
    asm volatile("" ::: "memory");              \
    __builtin_amdgcn_s_barrier();               \
    asm volatile("" ::: "memory");              \
  } while (0)
#define LGKM0() asm volatile("s_waitcnt lgkmcnt(0)" ::: "memory")
#define VMCNT6() asm volatile("s_waitcnt vmcnt(6)" ::: "memory")
#define VMCNT0() asm volatile("s_waitcnt vmcnt(0)" ::: "memory")

// fp32 -> bf16 conversion, 8 elements/thread (32B in, 16B out per lane).
__global__ __launch_bounds__(256) void cvt_kernel(
    const float* __restrict__ in, bf16* __restrict__ out, int n8) {
  int i = blockIdx.x * blockDim.x + threadIdx.x;
  if (i >= n8) return;
  const float4* p = (const float4*)in;
  float4 a = p[2 * i], b = p[2 * i + 1];
  union { bf16x8 v; bf16 h[8]; } u;
  u.h[0] = __float2bfloat16(a.x); u.h[1] = __float2bfloat16(a.y);
  u.h[2] = __float2bfloat16(a.z); u.h[3] = __float2bfloat16(a.w);
  u.h[4] = __float2bfloat16(b.x); u.h[5] = __float2bfloat16(b.y);
  u.h[6] = __float2bfloat16(b.z); u.h[7] = __float2bfloat16(b.w);
  ((bf16x8*)out)[i] = u.v;
}

// ============================================================================
// 256x256 8-phase GEMM (HK-style schedule, plain HIP).  C = A * B^T (+bias).
// A: [M][K] bf16, B: [N][K] bf16, fp32 accum, OutT out.
// 512 threads = 8 waves (2M x 4N); per-wave output 128x64 = acc[8][4] f32x4.
// BK=64; 2 K-tiles per loop iteration; 8 phases, 16 MFMA (one C-quadrant x
// K=64) per phase between raw barriers.
//
// LDS (128 KiB): sA[2][256*64], sB[2][256*64].  16B "slots": slot(rl,j) =
// rl*8 + (j ^ (rl&7))  -> read-side bank-conflict-free (T2).  global_load_lds
// writes linearly, so the SOURCE address is pre-swizzled (rule #21), and LDS
// rows are PERMUTED so each 128-row staging region = one read-phase's data:
//   A: lds row rl -> global row ((rl>>6)&1)*128 + ((rl>>7)&1)*64 + (rl&63)
//      (region [0,128) = qm=0 rows for both wm halves; [128,256) = qm=1)
//   B: lds row rl -> global row ((rl>>5)&3)*64 + ((rl>>7)&1)*32 + (rl&31)
//      (region [0,128) = qn=0 strips of all 4 wn; [128,256) = qn=1)
//
// Stage schedule (iter i computes tiles t0=2i (b0), t1=2i+1 (b1)):
//   ph1: A-odd(b1, t1)   ph2: A-even(b0, t0+2)  ph3: B-even(b0)  ph4: B-odd(b0)
//   ph5: A-odd(b0)       ph6: A-even(b1, t0+3)  ph7: B-even(b1)  ph8: B-odd(b1)
// Each stage targets a region whose reads completed >=1 barrier earlier.
// vmcnt(6) at END of ph4/ph8 (2 loads/half-tile x 3 half-tiles in flight)
// forces exactly the next buffer's 4 half-tiles to have landed -- loads are
// NEVER drained to 0 in the main loop (T4).  Ledger is wave-uniform.
// Tail: stage tile index clamped to NT-1 (harmless re-load, never read).
// ============================================================================

__device__ __forceinline__ bf16x8 ld_frag(const bf16* buf, int rl, int j) {
  return *(const bf16x8*)(buf + rl * 64 + ((j ^ (rl & 7)) << 3));
}

__device__ __forceinline__ void stage_halfA(const bf16* __restrict__ G,
                                            int row0, int K, int kt, bf16* buf,
                                            int r0, int wv, int lane) {
#pragma unroll
  for (int c = 0; c < 2; ++c) {
    const int sl = c * 512 + wv * 64 + lane;       // slot within 128-row region
    const int rl = r0 + (sl >> 3);
    const int j = (sl & 7) ^ (rl & 7);             // inverse swizzle on source
    const int grow = ((rl >> 6) & 1) * 128 + ((rl >> 7) & 1) * 64 + (rl & 63);
    async_load16(G + (size_t)(row0 + grow) * K + kt + j * 8,
                 buf + r0 * 64 + c * 4096 + wv * 512);  // linear LDS dest
  }
}

__device__ __forceinline__ void stage_halfB(const bf16* __restrict__ G,
                                            int row0, int K, int kt, bf16* buf,
                                            int r0, int wv, int lane) {
#pragma unroll
  for (int c = 0; c < 2; ++c) {
    const int sl = c * 512 + wv * 64 + lane;
    const int rl = r0 + (sl >> 3);
    const int j = (sl & 7) ^ (rl & 7);
    const int grow = ((rl >> 5) & 3) * 64 + ((rl >> 7) & 1) * 32 + (rl & 31);
    async_load16(G + (size_t)(row0 + grow) * K + kt + j * 8,
                 buf + r0 * 64 + c * 4096 + wv * 512);
  }
}

#define READ_A(DST, BUF, QM)                                                  \
  {                                                                           \
    _Pragma("unroll") for (int tm = 0; tm < 4; ++tm) {                        \
      _Pragma("unroll") for (int ks = 0; ks < 2; ++ks) {                      \
        DST[tm * 2 + ks] =                                                    \
            ld_frag(BUF, (QM) * 128 + wm * 64 + tm * 16 + l15, ks * 4 + quad);\
      }                                                                       \
    }                                                                         \
  }

#define READ_B(DST, BUF, QN)                                                  \
  {                                                                           \
    _Pragma("unroll") for (int tn = 0; tn < 2; ++tn) {                        \
      _Pragma("unroll") for (int ks = 0; ks < 2; ++ks) {                      \
        DST[tn * 2 + ks] =                                                    \
            ld_frag(BUF, (QN) * 128 + wn * 32 + tn * 16 + l15, ks * 4 + quad);\
      }                                                                       \
    }                                                                         \
  }

#define MFMA_Q(QM, QN, AF, BF)                                                \
  {                                                                           \
    __builtin_amdgcn_s_setprio(1);                                            \
    _Pragma("unroll") for (int tm = 0; tm < 4; ++tm) {                        \
      _Pragma("unroll") for (int tn = 0; tn < 2; ++tn) {                      \
        _Pragma("unroll") for (int ks = 0; ks < 2; ++ks) {                    \
          acc[(QM) * 4 + tm][(QN) * 2 + tn] =                                 \
              __builtin_amdgcn_mfma_f32_16x16x32_bf16(                        \
                  AF[tm * 2 + ks], BF[tn * 2 + ks],                           \
                  acc[(QM) * 4 + tm][(QN) * 2 + tn], 0, 0, 0);                \
        }                                                                     \
      }                                                                       \
    }                                                                         \
    __builtin_amdgcn_s_setprio(0);                                            \
  }

template <int BIAS, typename OutT>
__global__ __launch_bounds__(512, 2) void gemm256_kernel(
    const bf16* __restrict__ A, const bf16* __restrict__ B,
    const float* __restrict__ bias, OutT* __restrict__ C,
    int M, int N, int K) {
  __shared__ __attribute__((aligned(16))) bf16 sA[2][256 * 64];
  __shared__ __attribute__((aligned(16))) bf16 sB[2][256 * 64];

  const int tid = threadIdx.x;
  const int lane = tid & 63;
  const int wv = tid >> 6;   // 0..7
  const int wm = wv >> 2;    // 0..1 -> rows wm*128..+127 of the 256 tile
  const int wn = wv & 3;     // 0..3 -> cols wn*64..+63
  const int quad = lane >> 4;
  const int l15 = lane & 15;

  // T1: XCD-bijective block swizzle (launcher guarantees gridDim.x % 8 == 0).
  const int nwg = gridDim.x;
  const int bid = blockIdx.x;
  const int wg = (bid & 7) * (nwg >> 3) + (bid >> 3);
  const int nby = M >> 8;
  const int by = wg % nby;
  const int bx = wg / nby;   // consecutive wg on an XCD share bx -> B-panel L2-hot
  const int m0 = by * 256;
  const int n0 = bx * 256;

  const int NT = K >> 6;            // K-tiles of 64 (NT even: K % 128 == 0)
  const int klast = (NT - 1) << 6;

  f32x4 acc[8][4];
  const f32x4 zero = {0.f, 0.f, 0.f, 0.f};
#pragma unroll
  for (int i = 0; i < 8; ++i)
#pragma unroll
    for (int j = 0; j < 4; ++j) acc[i][j] = zero;

  // Prologue: tile0 -> b0 (all 4 halves, oldest 8 loads), tile1 -> b1
  // (A-even, B-even, B-odd; its A-odd is staged by ph1 of iteration 0).
  stage_halfA(A, m0, K, 0, sA[0], 0, wv, lane);
  stage_halfB(B, n0, K, 0, sB[0], 0, wv, lane);
  stage_halfB(B, n0, K, 0, sB[0], 128, wv, lane);
  stage_halfA(A, m0, K, 0, sA[0], 128, wv, lane);
  stage_halfA(A, m0, K, 64, sA[1], 0, wv, lane);
  stage_halfB(B, n0, K, 64, sB[1], 0, wv, lane);
  stage_halfB(B, n0, K, 64, sB[1], 128, wv, lane);
  VMCNT6();  // oldest 8 = all of tile0 landed; tile1's 6 may stay in flight
  BAR();

  for (int it = 0; it < (NT >> 1); ++it) {
    const int kt0 = it << 7;
    const int kt1 = kt0 + 64;
    const int ks0 = (kt0 + 128 < klast) ? kt0 + 128 : klast;  // tile 2it+2
    const int ks1 = (kt0 + 192 < klast) ? kt0 + 192 : klast;  // tile 2it+3

    bf16x8 a0f[8], a1f[8], b0f[4], b1f[4];

    // -------- buf0 = tile kt0 --------
    // ph1: quadrant (0,0)
    READ_A(a0f, sA[0], 0);
    READ_B(b0f, sB[0], 0);
    stage_halfA(A, m0, K, kt1, sA[1], 128, wv, lane);  // A-odd(b1), real tile
    BAR(); LGKM0();
    MFMA_Q(0, 0, a0f, b0f);
    BAR();
    // ph2: quadrant (0,1)
    READ_B(b1f, sB[0], 1);
    stage_halfA(A, m0, K, ks0, sA[0], 0, wv, lane);    // A-even(b0)
    BAR(); LGKM0();
    MFMA_Q(0, 1, a0f, b1f);
    BAR();
    // ph3: quadrant (1,0)
    READ_A(a1f, sA[0], 1);
    stage_halfB(B, n0, K, ks0, sB[0], 0, wv, lane);    // B-even(b0)
    BAR(); LGKM0();
    MFMA_Q(1, 0, a1f, b0f);
    BAR();
    // ph4: quadrant (1,1); end-of-tile vmcnt: forces tile (2it+1) resident
    stage_halfB(B, n0, K, ks0, sB[0], 128, wv, lane);  // B-odd(b0)
    BAR(); LGKM0();
    MFMA_Q(1, 1, a1f, b1f);
    VMCNT6();
    BAR();

    // -------- buf1 = tile kt1 --------
    // ph5: quadrant (0,0)
    READ_A(a0f, sA[1], 0);
    READ_B(b0f, sB[1], 0);
    stage_halfA(A, m0, K, ks0, sA[0], 128, wv, lane);  // A-odd(b0)
    BAR(); LGKM0();
    MFMA_Q(0, 0, a0f, b0f);
    BAR();
    // ph6: quadrant (0,1)
    READ_B(b1f, sB[1], 1);
    stage_halfA(A, m0, K, ks1, sA[1], 0, wv, lane);    // A-even(b1)
    BAR(); LGKM0();
    MFMA_Q(0, 1, a0f, b1f);
    BAR();
    // ph7: quadrant (1,0)
    READ_A(a1f, sA[1], 1);
    stage_halfB(B, n0, K, ks1, sB[1], 0, wv, lane);    // B-even(b1)
    BAR(); LGKM0();
    MFMA_Q(1, 0, a1f, b0f);
    BAR();
    // ph8: quadrant (1,1); end-of-tile vmcnt: forces tile (2it+2) resident
    stage_halfB(B, n0, K, ks1, sB[1], 128, wv, lane);  // B-odd(b1)
    BAR(); LGKM0();
    MFMA_Q(1, 1, a1f, b1f);
    VMCNT6();
    BAR();
  }

  VMCNT0();  // drain tail garbage stages before epilogue / endpgm

  // Epilogue. C/D layout (m89-verified): col = lane&15, row = quad*4 + reg.
#pragma unroll
  for (int mf = 0; mf < 8; ++mf) {
    const int row0 = m0 + wm * 128 + (mf >> 2) * 64 + (mf & 3) * 16 + quad * 4;
#pragma unroll
    for (int nf = 0; nf < 4; ++nf) {
      const int col = n0 + wn * 64 + (nf >> 1) * 32 + (nf & 1) * 16 + l15;
      float bv = 0.f;
      if (BIAS) bv = bias[col];
#pragma unroll
      for (int i = 0; i < 4; ++i) {
        float v = acc[mf][nf][i] + bv;
        if constexpr (sizeof(OutT) == 2)
          C[(size_t)(row0 + i) * N + col] = __float2bfloat16(v);
        else
          C[(size_t)(row0 + i) * N + col] = v;
      }
    }
  }
}

// Per-token head-attention: one block per token. (unchanged)
__global__ __launch_bounds__(256) void attn_kernel(
    const bf16* __restrict__ qkv, bf16* __restrict__ out) {
  const int b = blockIdx.x;
  const int tid = threadIdx.x;
  __shared__ uint32_t sQKV[3 * 32 * 65];
  __shared__ float S[32][33];

  const uint32_t* src = (const uint32_t*)(qkv + (size_t)b * 12288);
#pragma unroll
  for (int i = 0; i < 24; ++i) {
    int c = tid + i * 256;
    int sec = c >> 11;
    int cc = c & 2047;
    int row = cc >> 6;
    int col = cc & 63;
    sQKV[sec * 2080 + row * 65 + col] = src[c];
  }
  __syncthreads();

  const float scale = 0.088388347648318447f;  // 1/sqrt(128)
#pragma unroll
  for (int i = 0; i < 4; ++i) {
    int p = tid + i * 256;
    int h = p >> 5;
    int g = p & 31;
    const __hip_bfloat162* qr = (const __hip_bfloat162*)(sQKV + h * 65);
    const __hip_bfloat162* kr = (const __hip_bfloat162*)(sQKV + 2080 + g * 65);
    float acc = 0.f;
#pragma unroll
    for (int d = 0; d < 64; ++d) {
      float2 qf = __bfloat1622float2(qr[d]);
      float2 kf = __bfloat1622float2(kr[d]);
      acc = fmaf(qf.x, kf.x, acc);
      acc = fmaf(qf.y, kf.y, acc);
    }
    S[h][g] = acc * scale;
  }
  __syncthreads();

  if (tid < 32) {
    float m = -1e30f;
#pragma unroll
    for (int g = 0; g < 32; ++g) m = fmaxf(m, S[tid][g]);
    float sum = 0.f;
#pragma unroll
    for (int g = 0; g < 32; ++g) {
      float e = __expf(S[tid][g] - m);
      S[tid][g] = e;
      sum += e;
    }
    float inv = 1.f / sum;
#pragma unroll
    for (int g = 0; g < 32; ++g) S[tid][g] *= inv;
  }
  __syncthreads();

  const bf16* V = (const bf16*)(sQKV + 2 * 2080);
  bf16* orow = out + (size_t)b * 4096;
#pragma unroll
  for (int i = 0; i < 16; ++i) {
    int c = tid + i * 256;
    int d = c >> 5;
    int h = c & 31;
    float acc = 0.f;
#pragma unroll
    for (int g = 0; g < 32; ++g)
      acc = fmaf(S[h][g], __bfloat162float(V[g * 130 + d]), acc);
    orow[c] = __float2bfloat16(acc);
  }
}

extern "C" void kernel_launch(void* const* d_in, const int* in_sizes, int n_in,
                              void* d_out, int out_size, void* d_ws, size_t ws_size,
                              hipStream_t stream) {
  const float* x      = (const float*)d_in[0];
  const float* w_qkv  = (const float*)d_in[1];
  const float* w_proj = (const float*)d_in[2];
  const float* b_proj = (const float*)d_in[3];
  float* out = (float*)d_out;

  const int C = in_sizes[3];           // 4096
  const int B = in_sizes[0] / C;       // 8192

  bf16* xb    = (bf16*)d_ws;                    // B*C bf16
  bf16* wqb   = xb + (size_t)B * C;             // 3C*C bf16
  bf16* qkvb  = wqb + (size_t)3 * C * C;        // B*3C bf16
  bf16* attnb = xb;                             // reuse (x dead after GEMM1)
  bf16* wpb   = wqb;                            // reuse (w_qkv dead after GEMM1)

  const int nx = B * C / 8, nwq = 3 * C * C / 8, nwp = C * C / 8;
  cvt_kernel<<<(nx + 255) / 256, 256, 0, stream>>>(x, xb, nx);
  cvt_kernel<<<(nwq + 255) / 256, 256, 0, stream>>>(w_qkv, wqb, nwq);

  // 1) qkv = x @ w_qkv.T  (bf16 out).  grid = 48*32 = 1536 (%8==0)
  gemm256_kernel<0, bf16><<<(3 * C / 256) * (B / 256), 512, 0, stream>>>(
      xb, wqb, nullptr, qkvb, B, 3 * C, C);
  // 2) per-token head attention (+ transpose to (d*H + h) layout)
  attn_kernel<<<B, 256, 0, stream>>>(qkvb, attnb);
  // 3) out = attn_out @ w_proj.T + b_proj (fp32 out).  grid = 16*32 = 512
  cvt_kernel<<<(nwp + 255) / 256, 256, 0, stream>>>(w_proj, wpb, nwp);
  gemm256_kernel<1, float><<<(C / 256) * (B / 256), 512, 0, stream>>>(
      attnb, wpb, b_proj, out, B, C, C);
}